// Round 10
// baseline (1138.200 us; speedup 1.0000x reference)
//
#include <hip/hip_runtime.h>

#define NPTS 1024
#define NB 8
#define KNN 20
#define N3 (3*NPTS)
#define CHT 256           // total concatenated channels
#define BSX (CHT*N3)      // xfeat batch stride (floats)

// ---- workspace layout (float offsets) ----
constexpr int OFF_X0    = 0;                          // [B][3][N]
constexpr int OFF_XFEAT = OFF_X0 + NB*N3;             // [B][256][3][N]
constexpr int OFF_YAP   = OFF_XFEAT + NB*CHT*N3;      // [B][3][N][64]
constexpr int OFF_YBP   = OFF_YAP + NB*N3*64;
constexpr int OFF_YAD   = OFF_YBP + NB*N3*64;
constexpr int OFF_YBD   = OFF_YAD + NB*N3*64;
constexpr int OFF_XX    = OFF_YBD + NB*N3*64;         // [B][N]
constexpr int OFF_WCFT  = OFF_XX + NB*NPTS;           // [256][128]
constexpr int OFF_STATS = OFF_WCFT + 256*128;         // 5 layers x 256
constexpr int OFF_IDX   = OFF_STATS + 5*256;          // int32 [B][N][20]
constexpr int OFF_W4    = OFF_IDX + NB*NPTS*KNN;      // 4 layers x [64][64][4]
// final stage aliases (yA*/yB* dead after the layer loop):
constexpr int OFF_PF    = OFF_YAP;                    // [B][3][N][128]
constexpr int OFF_DF    = OFF_YAD;                    // [B][3][N]

// one-shot prep: transpose x, pack weights, transpose wcf, zero stats+out
__global__ __launch_bounds__(256) void k_prep(
    const float* __restrict__ x,
    const float* __restrict__ w1f, const float* __restrict__ w1d,
    const float* __restrict__ w2f, const float* __restrict__ w2d,
    const float* __restrict__ w3f, const float* __restrict__ w3d,
    const float* __restrict__ w4f, const float* __restrict__ w4d,
    const float* __restrict__ wcf,
    float* __restrict__ x0, float* __restrict__ w4, float* __restrict__ wT,
    float* __restrict__ stats, float* __restrict__ outz, int outn) {
  int blk = blockIdx.x, tid = threadIdx.x;
  if (blk < 32) {
    int t = blk*256 + tid;
    int b = t >> 10, n = t & 1023;
    const float* p = x + t*3;
    x0[b*N3 + n]          = p[0];
    x0[b*N3 + NPTS + n]   = p[1];
    x0[b*N3 + 2*NPTS + n] = p[2];
  } else if (blk == 32) {
    if (tid < 64) {
      int o = tid;
      float a0 = w1f[o*2], a1 = w1f[o*2+1];
      float d0 = w1d[o*2], d1 = w1d[o*2+1];
      float* dst = w4 + o*4;
      dst[0] = a0; dst[1] = a1 - a0; dst[2] = d0; dst[3] = d1 - d0;
    }
  } else if (blk < 36) {
    int L = blk - 32;                               // 1..3
    const float* wf = (L == 1) ? w2f : (L == 2) ? w3f : w4f;
    const float* wd = (L == 1) ? w2d : (L == 2) ? w3d : w4d;
    float* dst = w4 + L*16384;
    for (int u = 0; u < 64; ++u) {
      int e = tid + u*256;                          // [0,16384)
      int i = e >> 8, oc = e & 255, o = oc >> 2, c = oc & 3;
      float v;
      if (c == 0)      v = wf[o*128 + i];
      else if (c == 1) v = wf[o*128 + 64 + i] - wf[o*128 + i];
      else if (c == 2) v = wd[o*128 + i];
      else             v = wd[o*128 + 64 + i] - wd[o*128 + i];
      dst[e] = v;
    }
  } else if (blk < 40) {
    int e0 = (blk - 36) * 8192;
    for (int u = 0; u < 32; ++u) {
      int e = e0 + tid + u*256;
      int o = e >> 8, i = e & 255;
      wT[i*128 + o] = wcf[e];
    }
  } else {
    for (int e = tid; e < 5*256; e += 256) stats[e] = 0.f;
    for (int e = tid; e < outn; e += 256) outz[e] = 0.f;
  }
}

// per-point squared norm, SINGLE ascending-d fmaf chain (matches the Gram
// diagonal's accumulation order in k_knn5 -> self-distance exactly 0)
__global__ void k_xx(const float* __restrict__ Fb, int bs, int D, float* __restrict__ xx) {
  int t = blockIdx.x*256 + threadIdx.x;
  int b = t >> 10, m = t & 1023;
  const float* f = Fb + (size_t)b*bs + m;
  float a = 0.f;
  for (int d = 0; d < D; ++d) { float v = f[d*NPTS]; a = fmaf(v, v, a); }
  xx[t] = a;
}

// kNN v5: 256 blocks x 512 threads; wave owns 4 rows (rf via one b128) x 1024 m.
// Gram amortizes xm LDS reads over 4 rows (128 FMA per 5 b128). Topk (u64-key
// butterfly, proven in knn2) runs per row-PAIR to cap live VGPRs.
__global__ __launch_bounds__(512) void k_knn5(const float* __restrict__ Fb, int bs, int D,
                                              const float* __restrict__ xx,
                                              int* __restrict__ idxo) {
  __shared__ float xs[8][NPTS];          // 32 KB
  int g  = blockIdx.x;
  int wg = (g & 7)*32 + (g >> 3);        // XCD swizzle: batch -> one XCD (8x32)
  int b  = wg >> 5;
  int n0 = (wg & 31) << 5;               // 32 rows/block
  int tid = threadIdx.x;
  int w = tid >> 6, lane = tid & 63;
  int rowbase = n0 + (w << 2);           // 4 consecutive rows per wave
  const float* f = Fb + (size_t)b*bs;

  float acc0[16], acc1[16], acc2[16], acc3[16];
  #pragma unroll
  for (int s = 0; s < 16; ++s) { acc0[s] = 0.f; acc1[s] = 0.f; acc2[s] = 0.f; acc3[s] = 0.f; }

  int nt = (D + 7) >> 3;
  for (int t = 0; t < nt; ++t) {
    int d0 = t << 3;
    int cnt = D - d0; if (cnt > 8) cnt = 8;
    __syncthreads();
    #pragma unroll
    for (int u = 0; u < 4; ++u) {
      int e = tid + (u << 9);
      int dd = e >> 8, mq = (e & 255) << 2;
      if (dd < cnt)
        *(float4*)&xs[dd][mq] = *(const float4*)&f[(size_t)(d0 + dd)*NPTS + mq];
    }
    __syncthreads();
    for (int dd = 0; dd < cnt; ++dd) {
      float4 rf = *(const float4*)&xs[dd][rowbase];   // 4 rows, one b128
      #pragma unroll
      for (int s2 = 0; s2 < 4; ++s2) {
        float4 xm = *(const float4*)&xs[dd][(lane << 2) + (s2 << 8)];
        float xm4[4] = {xm.x, xm.y, xm.z, xm.w};
        #pragma unroll
        for (int q = 0; q < 4; ++q) {
          int s = s2*4 + q;
          acc0[s] = fmaf(rf.x, xm4[q], acc0[s]);
          acc1[s] = fmaf(rf.y, xm4[q], acc1[s]);
          acc2[s] = fmaf(rf.z, xm4[q], acc2[s]);
          acc3[s] = fmaf(rf.w, xm4[q], acc3[s]);
        }
      }
    }
  }

  // topk per row-pair: finalize neg-dist (ref op order), convert to monotone
  // u32 keys in place, u64-key butterfly (proven knn2 code).
  unsigned base4L = (unsigned)(lane << 2);
  #pragma unroll
  for (int pr = 0; pr < 2; ++pr) {
    float* accA = (pr == 0) ? acc0 : acc2;
    float* accB = (pr == 0) ? acc1 : acc3;
    int rowA = rowbase + pr*2, rowB = rowA + 1;
    unsigned ordA[16], ordB[16];
    float xxrA = xx[b*NPTS + rowA];
    float xxrB = xx[b*NPTS + rowB];
    #pragma unroll
    for (int s2 = 0; s2 < 4; ++s2) {
      float4 xv = *(const float4*)&xx[b*NPTS + (lane << 2) + (s2 << 8)];
      float xm4[4] = {xv.x, xv.y, xv.z, xv.w};
      #pragma unroll
      for (int q = 0; q < 4; ++q) {
        int s = s2*4 + q;
        float vA = (2.f*accA[s] - xxrA) - xm4[q];
        float vB = (2.f*accB[s] - xxrB) - xm4[q];
        unsigned uA = __float_as_uint(vA);
        unsigned uB = __float_as_uint(vB);
        ordA[s] = (uA & 0x80000000u) ? ~uA : (uA | 0x80000000u);
        ordB[s] = (uB & 0x80000000u) ? ~uB : (uB | 0x80000000u);
      }
    }
    unsigned clA = 0xFFFFFFFFu, clB = 0xFFFFFFFFu;
    int winmA = 0, winmB = 0;
    for (int it = 0; it < KNN; ++it) {
      unsigned boA = 0u, bcA = 0u, boB = 0u, bcB = 0u;
      #pragma unroll
      for (int s = 0; s < 16; ++s) {
        const unsigned Cs = (unsigned)(((s >> 2) << 8) | (s & 3));
        unsigned vA = ordA[s]; vA = (clA == Cs) ? 0u : vA; ordA[s] = vA;
        if (vA > boA) { boA = vA; bcA = Cs; }   // strict > : lowest m wins in-lane
        unsigned vB = ordB[s]; vB = (clB == Cs) ? 0u : vB; ordB[s] = vB;
        if (vB > boB) { boB = vB; bcB = Cs; }
      }
      unsigned mA = base4L + bcA, mB = base4L + bcB;
      unsigned long long KA = ((unsigned long long)boA << 32) | (unsigned long long)(1023u - mA);
      unsigned long long KB = ((unsigned long long)boB << 32) | (unsigned long long)(1023u - mB);
      unsigned long long myKA = KA, myKB = KB;
      #pragma unroll
      for (int off = 1; off < 64; off <<= 1) {
        unsigned long long oA = __shfl_xor(KA, off, 64);
        unsigned long long oB = __shfl_xor(KB, off, 64);
        KA = (oA > KA) ? oA : KA;               // keys unique (m packed) -> no tie
        KB = (oB > KB) ? oB : KB;
      }
      clA = (KA == myKA) ? bcA : 0xFFFFFFFFu;
      clB = (KB == myKB) ? bcB : 0xFFFFFFFFu;
      if (lane == it) {
        winmA = 1023 - (int)(unsigned)(KA & 0xFFFFFFFFull);
        winmB = 1023 - (int)(unsigned)(KB & 0xFFFFFFFFull);
      }
    }
    if (lane < KNN) {
      idxo[(b*NPTS + rowA)*KNN + lane] = winmA;
      idxo[(b*NPTS + rowB)*KNN + lane] = winmB;
    }
  }
}

// fused F+D linear: yAp/yBp/yAd/yBd from packed w4 [i][o][4] = {aF,bF,aD,bD}
__global__ __launch_bounds__(256) void k_linear4(const float* __restrict__ xin, int bsx,
                                                 const float* __restrict__ w4, int DIN,
                                                 float* __restrict__ yAp, float* __restrict__ yBp,
                                                 float* __restrict__ yAd, float* __restrict__ yBd) {
  int tid = threadIdx.x;
  int o = tid & 63, ns = tid >> 6;
  int b = blockIdx.y / 3, v = blockIdx.y % 3;
  int n0 = blockIdx.x * 32 + ns * 8;
  const float* xb = xin + (size_t)b*bsx + v*NPTS + n0;
  float aF[8], bF[8], aD[8], bD[8];
  #pragma unroll
  for (int j = 0; j < 8; ++j) { aF[j] = 0.f; bF[j] = 0.f; aD[j] = 0.f; bD[j] = 0.f; }
  #pragma unroll 4
  for (int i = 0; i < DIN; ++i) {
    float4 wv  = *(const float4*)&w4[(i << 8) + (o << 2)];
    float4 xlo = *(const float4*)&xb[i*N3];
    float4 xhi = *(const float4*)&xb[i*N3 + 4];
    float xv[8] = {xlo.x, xlo.y, xlo.z, xlo.w, xhi.x, xhi.y, xhi.z, xhi.w};
    #pragma unroll
    for (int j = 0; j < 8; ++j) {
      aF[j] = fmaf(wv.x, xv[j], aF[j]);
      bF[j] = fmaf(wv.y, xv[j], bF[j]);
      aD[j] = fmaf(wv.z, xv[j], aD[j]);
      bD[j] = fmaf(wv.w, xv[j], bD[j]);
    }
  }
  int base = ((b*3 + v)*NPTS + n0)*64 + o;
  #pragma unroll
  for (int j = 0; j < 8; ++j) {
    yAp[base + j*64] = aF[j];
    yBp[base + j*64] = bF[j];
    yAd[base + j*64] = aD[j];
    yBd[base + j*64] = bD[j];
  }
}

// per-channel sum/sumsq of ||p||+eps; 2048 blocks, XCD-batch swizzle
__global__ __launch_bounds__(256) void k_stats2(const float* __restrict__ yAp, const float* __restrict__ yBp,
                                                const int* __restrict__ idxo, float* __restrict__ statsL) {
  __shared__ float rs[256], rss[256];
  int tid = threadIdx.x; int o = tid & 63, w = tid >> 6;
  int blk = blockIdx.x;
  int wg = ((blk & 7) << 8) | (blk >> 3);
  int b = wg >> 8;
  int n = ((wg & 255) << 2) + w;
  const int* ir = idxo + (b*NPTS + n)*KNN;
  int4 ir0 = *(const int4*)&ir[0],  ir1 = *(const int4*)&ir[4];
  int4 ir2 = *(const int4*)&ir[8],  ir3 = *(const int4*)&ir[12];
  int4 ir4 = *(const int4*)&ir[16];
  int mm[20] = {ir0.x,ir0.y,ir0.z,ir0.w, ir1.x,ir1.y,ir1.z,ir1.w,
                ir2.x,ir2.y,ir2.z,ir2.w, ir3.x,ir3.y,ir3.z,ir3.w,
                ir4.x,ir4.y,ir4.z,ir4.w};
  int i0 = (b*3*NPTS + n)*64 + o;
  float c0 = yBp[i0], c1 = yBp[i0 + NPTS*64], c2 = yBp[i0 + 2*NPTS*64];
  float s = 0.f, ss = 0.f;
  #pragma unroll
  for (int kk = 0; kk < KNN; ++kk) {
    int m = mm[kk];
    int gg = (b*3*NPTS + m)*64 + o;
    float p0 = yAp[gg] + c0;
    float p1 = yAp[gg + NPTS*64] + c1;
    float p2 = yAp[gg + 2*NPTS*64] + c2;
    float nrm = sqrtf(p0*p0 + p1*p1 + p2*p2) + 1e-6f;
    s += nrm; ss = fmaf(nrm, nrm, ss);
  }
  rs[tid] = s; rss[tid] = ss;
  __syncthreads();
  if (tid < 64) {
    float a  = rs[tid]  + rs[tid+64]  + rs[tid+128]  + rs[tid+192];
    float as = rss[tid] + rss[tid+64] + rss[tid+128] + rss[tid+192];
    atomicAdd(&statsL[tid], a);
    atomicAdd(&statsL[128 + tid], as);
  }
}

// BN + directional LeakyReLU + mean over k -> xfeat slice (XCD-batch swizzle)
__global__ __launch_bounds__(256) void k_apply(const float* __restrict__ yAp, const float* __restrict__ yBp,
                                               const float* __restrict__ yAd, const float* __restrict__ yBd,
                                               const int* __restrict__ idxo, const float* __restrict__ statsL,
                                               const float* __restrict__ bnw, const float* __restrict__ bnb,
                                               float* __restrict__ xfeat, int coff) {
  int tid = threadIdx.x; int o = tid & 63, w = tid >> 6;
  int blk = blockIdx.x;
  int wg = ((blk & 7) << 8) | (blk >> 3);
  int b = wg >> 8;
  int n = ((wg & 255) << 2) + w;
  const float cntInv = 1.f / 163840.f;
  float mean = statsL[o] * cntInv;
  float var  = statsL[128 + o] * cntInv - mean*mean;
  float istd = rsqrtf(var + 1e-5f);
  float wN = bnw[o], bN = bnb[o];
  int i0 = (b*3*NPTS + n)*64 + o;
  float cp0 = yBp[i0], cp1 = yBp[i0 + NPTS*64], cp2 = yBp[i0 + 2*NPTS*64];
  float cd0 = yBd[i0], cd1 = yBd[i0 + NPTS*64], cd2 = yBd[i0 + 2*NPTS*64];
  const int* ir = idxo + (b*NPTS + n)*KNN;
  int4 ir0 = *(const int4*)&ir[0],  ir1 = *(const int4*)&ir[4];
  int4 ir2 = *(const int4*)&ir[8],  ir3 = *(const int4*)&ir[12];
  int4 ir4 = *(const int4*)&ir[16];
  int mm[20] = {ir0.x,ir0.y,ir0.z,ir0.w, ir1.x,ir1.y,ir1.z,ir1.w,
                ir2.x,ir2.y,ir2.z,ir2.w, ir3.x,ir3.y,ir3.z,ir3.w,
                ir4.x,ir4.y,ir4.z,ir4.w};
  float a0 = 0.f, a1 = 0.f, a2 = 0.f;
  #pragma unroll
  for (int kk = 0; kk < KNN; ++kk) {
    int m = mm[kk];
    int gg = (b*3*NPTS + m)*64 + o;
    float p0 = yAp[gg] + cp0, p1 = yAp[gg + NPTS*64] + cp1, p2 = yAp[gg + 2*NPTS*64] + cp2;
    float d0 = yAd[gg] + cd0, d1 = yAd[gg + NPTS*64] + cd1, d2 = yAd[gg + 2*NPTS*64] + cd2;
    float nrm = sqrtf(p0*p0 + p1*p1 + p2*p2) + 1e-6f;
    float sc = ((nrm - mean)*istd*wN + bN) / nrm;
    p0 *= sc; p1 *= sc; p2 *= sc;
    float dot = p0*d0 + p1*d1 + p2*d2;
    float dsq = d0*d0 + d1*d1 + d2*d2;
    float coef = (dot < 0.f) ? (0.8f * dot / (dsq + 1e-6f)) : 0.f;
    a0 += p0 - coef*d0; a1 += p1 - coef*d1; a2 += p2 - coef*d2;
  }
  int ob = ((b*CHT + coff + o)*3)*NPTS + n;
  xfeat[ob]          = a0 * 0.05f;
  xfeat[ob + NPTS]   = a1 * 0.05f;
  xfeat[ob + 2*NPTS] = a2 * 0.05f;
}

// pF = wcf * cat (16-n LDS tile, 1536 blocks for occupancy); dF fused
__global__ __launch_bounds__(256) void k_pF4(const float* __restrict__ xfeat, const float* __restrict__ wT,
                                             const float* __restrict__ wcd,
                                             float* __restrict__ pF, float* __restrict__ dF) {
  __shared__ float xs[256][16];          // 16 KB
  __shared__ float dpart[16][16];
  int tid = threadIdx.x;
  int b = blockIdx.y / 3, v = blockIdx.y % 3;
  int n0 = blockIdx.x * 16;
  const float* xb = xfeat + (size_t)b*BSX + v*NPTS + n0;
  #pragma unroll
  for (int u = 0; u < 4; ++u) {
    int e = tid + (u << 8);              // 0..1023
    int i = e >> 2, sl = (e & 3) << 2;
    *(float4*)&xs[i][sl] = *(const float4*)&xb[(size_t)i*N3 + sl];
  }
  __syncthreads();
  int o = tid & 127, h = tid >> 7;       // h: n-half (8 each)
  float a[8];
  #pragma unroll
  for (int j = 0; j < 8; ++j) a[j] = 0.f;
  for (int i = 0; i < 256; ++i) {
    float wv = wT[i*128 + o];
    #pragma unroll
    for (int q = 0; q < 2; ++q) {
      float4 xv = *(const float4*)&xs[i][h*8 + q*4];
      a[q*4+0] = fmaf(wv, xv.x, a[q*4+0]);
      a[q*4+1] = fmaf(wv, xv.y, a[q*4+1]);
      a[q*4+2] = fmaf(wv, xv.z, a[q*4+2]);
      a[q*4+3] = fmaf(wv, xv.w, a[q*4+3]);
    }
  }
  int base = ((b*3 + v)*NPTS + n0 + h*8)*128 + o;
  #pragma unroll
  for (int j = 0; j < 8; ++j) pF[base + j*128] = a[j];
  int nn = tid & 15, gI = tid >> 4;      // 16 groups x 16 i
  float dp = 0.f;
  for (int i = gI*16; i < gI*16 + 16; ++i) dp = fmaf(wcd[i], xs[i][nn], dp);
  dpart[gI][nn] = dp;
  __syncthreads();
  if (tid < 16) {
    float aa = 0.f;
    #pragma unroll
    for (int gq = 0; gq < 16; ++gq) aa += dpart[gq][tid];
    dF[(b*3 + v)*NPTS + n0 + tid] = aa;
  }
}

__global__ __launch_bounds__(256) void k_statsF2(const float* __restrict__ pF, float* __restrict__ statsF) {
  int tid = threadIdx.x; int o = tid & 127, half = tid >> 7;
  int blk = blockIdx.x;
  int b = blk >> 6, n0 = (blk & 63) << 4;
  float s = 0.f, ss = 0.f;
  for (int j = 0; j < 8; ++j) {
    int n = n0 + half + (j << 1);
    int g = (b*3*NPTS + n)*128 + o;
    float p0 = pF[g], p1 = pF[g + NPTS*128], p2 = pF[g + 2*NPTS*128];
    float nrm = sqrtf(p0*p0 + p1*p1 + p2*p2) + 1e-6f;
    s += nrm; ss = fmaf(nrm, nrm, ss);
  }
  atomicAdd(&statsF[o], s);
  atomicAdd(&statsF[128 + o], ss);
}

__global__ __launch_bounds__(256) void k_final2(const float* __restrict__ pF, const float* __restrict__ dF,
                                                const float* __restrict__ statsF,
                                                const float* __restrict__ bncw, const float* __restrict__ bncb,
                                                float* __restrict__ out) {
  int tid = threadIdx.x; int o = tid & 127, half = tid >> 7;
  int blk = blockIdx.x;
  int b = blk >> 5, n0 = (blk & 31) << 5;
  const float cntInv = 1.f / 8192.f;
  float mean = statsF[o] * cntInv;
  float var  = statsF[128 + o] * cntInv - mean*mean;
  float istd = rsqrtf(var + 1e-5f);
  float wN = bncw[o], bN = bncb[o];
  float a0 = 0.f, a1 = 0.f, a2 = 0.f;
  for (int j = 0; j < 16; ++j) {
    int n = n0 + half + (j << 1);
    int g = (b*3*NPTS + n)*128 + o;
    float p0 = pF[g], p1 = pF[g + NPTS*128], p2 = pF[g + 2*NPTS*128];
    int dg = b*N3 + n;
    float d0 = dF[dg], d1 = dF[dg + NPTS], d2 = dF[dg + 2*NPTS];
    float nrm = sqrtf(p0*p0 + p1*p1 + p2*p2) + 1e-6f;
    float sc = ((nrm - mean)*istd*wN + bN) / nrm;
    p0 *= sc; p1 *= sc; p2 *= sc;
    float dot = p0*d0 + p1*d1 + p2*d2;
    float dsq = d0*d0 + d1*d1 + d2*d2;
    float coef = (dot < 0.f) ? (0.8f * dot / (dsq + 1e-6f)) : 0.f;
    a0 += p0 - coef*d0; a1 += p1 - coef*d1; a2 += p2 - coef*d2;
  }
  float scl = 1.f / 1024.f;
  int ob = (b*128 + o)*3;
  atomicAdd(&out[ob],     a0*scl);
  atomicAdd(&out[ob + 1], a1*scl);
  atomicAdd(&out[ob + 2], a2*scl);
}

extern "C" void kernel_launch(void* const* d_in, const int* in_sizes, int n_in,
                              void* d_out, int out_size, void* d_ws, size_t ws_size,
                              hipStream_t stream) {
  (void)in_sizes; (void)n_in; (void)ws_size;
  const float* x = (const float*)d_in[0];
  const float* bnW[4] = {(const float*)d_in[3],  (const float*)d_in[7],
                         (const float*)d_in[11], (const float*)d_in[15]};
  const float* bnB[4] = {(const float*)d_in[4],  (const float*)d_in[8],
                         (const float*)d_in[12], (const float*)d_in[16]};
  const float* wcf  = (const float*)d_in[17];
  const float* wcd  = (const float*)d_in[18];
  const float* bncw = (const float*)d_in[19];
  const float* bncb = (const float*)d_in[20];

  float* ws    = (float*)d_ws;
  float* x0    = ws + OFF_X0;
  float* xfeat = ws + OFF_XFEAT;
  float* yAp   = ws + OFF_YAP;
  float* yBp   = ws + OFF_YBP;
  float* yAd   = ws + OFF_YAD;
  float* yBd   = ws + OFF_YBD;
  float* pF    = ws + OFF_PF;   // aliases yAp/yBp (dead by then)
  float* dF    = ws + OFF_DF;   // aliases yAd
  float* xx    = ws + OFF_XX;
  float* wT    = ws + OFF_WCFT;
  float* stats = ws + OFF_STATS;
  int*   idx   = (int*)(ws + OFF_IDX);
  float* w4    = ws + OFF_W4;

  k_prep<<<41, 256, 0, stream>>>(x,
      (const float*)d_in[1], (const float*)d_in[2],
      (const float*)d_in[5], (const float*)d_in[6],
      (const float*)d_in[9], (const float*)d_in[10],
      (const float*)d_in[13], (const float*)d_in[14],
      wcf, x0, w4, wT, stats, (float*)d_out, out_size);

  for (int L = 0; L < 4; ++L) {
    const float* fin = (L == 0) ? x0 : (xfeat + (L-1)*64*N3);
    int bs = (L == 0) ? N3 : BSX;
    int D  = (L == 0) ? 3 : 192;
    int DIN = (L == 0) ? 1 : 64;
    k_xx<<<NB*NPTS/256, 256, 0, stream>>>(fin, bs, D, xx);
    k_knn5<<<256, 512, 0, stream>>>(fin, bs, D, xx, idx);
    k_linear4<<<dim3(32, 24), 256, 0, stream>>>(fin, bs, w4 + L*16384, DIN,
                                                yAp, yBp, yAd, yBd);
    k_stats2<<<2048, 256, 0, stream>>>(yAp, yBp, idx, stats + L*256);
    k_apply<<<2048, 256, 0, stream>>>(yAp, yBp, yAd, yBd, idx, stats + L*256,
                                      bnW[L], bnB[L], xfeat, L*64);
  }

  k_pF4<<<dim3(64, 24), 256, 0, stream>>>(xfeat, wT, wcd, pF, dF);
  k_statsF2<<<512, 256, 0, stream>>>(pF, stats + 4*256);
  k_final2<<<256, 256, 0, stream>>>(pF, dF, stats + 4*256, bncw, bncb, (float*)d_out);
}

// Round 11
// 954.006 us; speedup vs baseline: 1.1931x; 1.1931x over previous
//
#include <hip/hip_runtime.h>

#define NPTS 1024
#define NB 8
#define KNN 20
#define N3 (3*NPTS)
#define CHT 256           // total concatenated channels
#define BSX (CHT*N3)      // xfeat batch stride (floats)

// ---- workspace layout (float offsets) ----
constexpr int OFF_X0    = 0;                          // [B][3][N]
constexpr int OFF_XFEAT = OFF_X0 + NB*N3;             // [B][256][3][N]
constexpr int OFF_YAP   = OFF_XFEAT + NB*CHT*N3;      // [B][3][N][64]
constexpr int OFF_YBP   = OFF_YAP + NB*N3*64;
constexpr int OFF_YAD   = OFF_YBP + NB*N3*64;
constexpr int OFF_YBD   = OFF_YAD + NB*N3*64;
constexpr int OFF_XX    = OFF_YBD + NB*N3*64;         // [B][N]
constexpr int OFF_WCFT  = OFF_XX + NB*NPTS;           // [256][128]
constexpr int OFF_STATS = OFF_WCFT + 256*128;         // 5 layers x 256
constexpr int OFF_IDX   = OFF_STATS + 5*256;          // int32 [B][N][20]
constexpr int OFF_W4    = OFF_IDX + NB*NPTS*KNN;      // 4 layers x [64][64][4]
// final stage aliases (yA*/yB* dead after the layer loop):
constexpr int OFF_PF    = OFF_YAP;                    // [B][3][N][128]
constexpr int OFF_DF    = OFF_YAD;                    // [B][3][N]

// one-shot prep: transpose x, pack weights, transpose wcf, zero stats+out
__global__ __launch_bounds__(256) void k_prep(
    const float* __restrict__ x,
    const float* __restrict__ w1f, const float* __restrict__ w1d,
    const float* __restrict__ w2f, const float* __restrict__ w2d,
    const float* __restrict__ w3f, const float* __restrict__ w3d,
    const float* __restrict__ w4f, const float* __restrict__ w4d,
    const float* __restrict__ wcf,
    float* __restrict__ x0, float* __restrict__ w4, float* __restrict__ wT,
    float* __restrict__ stats, float* __restrict__ outz, int outn) {
  int blk = blockIdx.x, tid = threadIdx.x;
  if (blk < 32) {
    int t = blk*256 + tid;
    int b = t >> 10, n = t & 1023;
    const float* p = x + t*3;
    x0[b*N3 + n]          = p[0];
    x0[b*N3 + NPTS + n]   = p[1];
    x0[b*N3 + 2*NPTS + n] = p[2];
  } else if (blk == 32) {
    if (tid < 64) {
      int o = tid;
      float a0 = w1f[o*2], a1 = w1f[o*2+1];
      float d0 = w1d[o*2], d1 = w1d[o*2+1];
      float* dst = w4 + o*4;
      dst[0] = a0; dst[1] = a1 - a0; dst[2] = d0; dst[3] = d1 - d0;
    }
  } else if (blk < 36) {
    int L = blk - 32;                               // 1..3
    const float* wf = (L == 1) ? w2f : (L == 2) ? w3f : w4f;
    const float* wd = (L == 1) ? w2d : (L == 2) ? w3d : w4d;
    float* dst = w4 + L*16384;
    for (int u = 0; u < 64; ++u) {
      int e = tid + u*256;                          // [0,16384)
      int i = e >> 8, oc = e & 255, o = oc >> 2, c = oc & 3;
      float v;
      if (c == 0)      v = wf[o*128 + i];
      else if (c == 1) v = wf[o*128 + 64 + i] - wf[o*128 + i];
      else if (c == 2) v = wd[o*128 + i];
      else             v = wd[o*128 + 64 + i] - wd[o*128 + i];
      dst[e] = v;
    }
  } else if (blk < 40) {
    int e0 = (blk - 36) * 8192;
    for (int u = 0; u < 32; ++u) {
      int e = e0 + tid + u*256;
      int o = e >> 8, i = e & 255;
      wT[i*128 + o] = wcf[e];
    }
  } else {
    for (int e = tid; e < 5*256; e += 256) stats[e] = 0.f;
    for (int e = tid; e < outn; e += 256) outz[e] = 0.f;
  }
}

// per-point squared norm: 512 blocks, 16 points x 16 d-chunks, LDS reduce.
// (Chunked order != Gram chain -> diagonal ~1-2 ulp off 0; harmless: self
// still ranks first unless duplicate points exist. R4/R8 precedent passed.)
__global__ __launch_bounds__(256) void k_xx3(const float* __restrict__ Fb, int bs, int D,
                                             float* __restrict__ xx) {
  __shared__ float sm[16][17];
  int tid = threadIdx.x;
  int p = tid & 15, c = tid >> 4;           // 16 points, 16 chunks
  int t = blockIdx.x * 16 + p;
  int b = t >> 10, m = t & 1023;
  int s = (D * c) >> 4, e = (D * (c + 1)) >> 4;
  const float* f = Fb + (size_t)b*bs + m;
  float a = 0.f;
  for (int d = s; d < e; ++d) { float v = f[d*NPTS]; a = fmaf(v, v, a); }
  sm[c][p] = a;
  __syncthreads();
  if (c == 0) {
    float acc = sm[0][p];
    #pragma unroll
    for (int q = 1; q < 16; ++q) acc += sm[q][p];
    xx[t] = acc;
  }
}

// kNN (proven): 512 blocks x 512 threads; block = 16 query rows; Gram in regs
// via 32KB LDS tile (2 blocks/CU -> staging/compute overlap); top-20 via
// u64-key butterfly, two rows interleaved for ILP.
__global__ __launch_bounds__(512) void k_knn2(const float* __restrict__ Fb, int bs, int D,
                                              const float* __restrict__ xx,
                                              int* __restrict__ idxo) {
  __shared__ float xs[8][NPTS];          // 32 KB
  int g  = blockIdx.x;
  int wg = (g & 7)*64 + (g >> 3);        // XCD swizzle: batch -> one XCD
  int b  = wg >> 6;
  int n0 = (wg & 63) << 4;
  int tid = threadIdx.x;
  int w = tid >> 6, lane = tid & 63;
  const float* f = Fb + (size_t)b*bs;

  int row0 = n0 + 2*w, row1 = row0 + 1;
  float acc0[16], acc1[16];
  #pragma unroll
  for (int s = 0; s < 16; ++s) { acc0[s] = 0.f; acc1[s] = 0.f; }

  int nt = (D + 7) >> 3;
  for (int t = 0; t < nt; ++t) {
    int d0 = t << 3;
    int cnt = D - d0; if (cnt > 8) cnt = 8;
    __syncthreads();
    #pragma unroll
    for (int u = 0; u < 4; ++u) {
      int e = tid + (u << 9);
      int dd = e >> 8, mq = (e & 255) << 2;
      if (dd < cnt)
        *(float4*)&xs[dd][mq] = *(const float4*)&f[(size_t)(d0 + dd)*NPTS + mq];
    }
    __syncthreads();
    for (int dd = 0; dd < cnt; ++dd) {
      float rf0 = xs[dd][row0];
      float rf1 = xs[dd][row1];
      #pragma unroll
      for (int s2 = 0; s2 < 4; ++s2) {
        float4 xm = *(const float4*)&xs[dd][(lane << 2) + (s2 << 8)];
        acc0[s2*4+0] = fmaf(rf0, xm.x, acc0[s2*4+0]);
        acc0[s2*4+1] = fmaf(rf0, xm.y, acc0[s2*4+1]);
        acc0[s2*4+2] = fmaf(rf0, xm.z, acc0[s2*4+2]);
        acc0[s2*4+3] = fmaf(rf0, xm.w, acc0[s2*4+3]);
        acc1[s2*4+0] = fmaf(rf1, xm.x, acc1[s2*4+0]);
        acc1[s2*4+1] = fmaf(rf1, xm.y, acc1[s2*4+1]);
        acc1[s2*4+2] = fmaf(rf1, xm.z, acc1[s2*4+2]);
        acc1[s2*4+3] = fmaf(rf1, xm.w, acc1[s2*4+3]);
      }
    }
  }

  // finalize neg-dist (ref op order) and convert to monotone 32-bit order keys
  unsigned ord0[16], ord1[16];
  float xxr0 = xx[b*NPTS + row0];
  float xxr1 = xx[b*NPTS + row1];
  #pragma unroll
  for (int s2 = 0; s2 < 4; ++s2) {
    float4 xv = *(const float4*)&xx[b*NPTS + (lane << 2) + (s2 << 8)];
    float xm4[4] = {xv.x, xv.y, xv.z, xv.w};
    #pragma unroll
    for (int q = 0; q < 4; ++q) {
      int s = s2*4 + q;
      float v0 = (2.f*acc0[s] - xxr0) - xm4[q];
      float v1 = (2.f*acc1[s] - xxr1) - xm4[q];
      unsigned u0 = __float_as_uint(v0);
      unsigned u1 = __float_as_uint(v1);
      ord0[s] = (u0 & 0x80000000u) ? ~u0 : (u0 | 0x80000000u);
      ord1[s] = (u1 & 0x80000000u) ? ~u1 : (u1 | 0x80000000u);
    }
  }

  unsigned base4L = (unsigned)(lane << 2);
  unsigned cl0 = 0xFFFFFFFFu, cl1 = 0xFFFFFFFFu;   // slot-code to clear (winner only)
  int winm0 = 0, winm1 = 0;
  for (int it = 0; it < KNN; ++it) {
    unsigned bo0 = 0u, bc0 = 0u, bo1 = 0u, bc1 = 0u;
    #pragma unroll
    for (int s = 0; s < 16; ++s) {
      const unsigned Cs = (unsigned)(((s >> 2) << 8) | (s & 3));
      unsigned v0 = ord0[s]; v0 = (cl0 == Cs) ? 0u : v0; ord0[s] = v0;
      if (v0 > bo0) { bo0 = v0; bc0 = Cs; }     // strict > : lowest m wins in-lane
      unsigned v1 = ord1[s]; v1 = (cl1 == Cs) ? 0u : v1; ord1[s] = v1;
      if (v1 > bo1) { bo1 = v1; bc1 = Cs; }
    }
    unsigned m0 = base4L + bc0, m1 = base4L + bc1;
    unsigned long long K0 = ((unsigned long long)bo0 << 32) | (unsigned long long)(1023u - m0);
    unsigned long long K1 = ((unsigned long long)bo1 << 32) | (unsigned long long)(1023u - m1);
    unsigned long long myK0 = K0, myK1 = K1;
    #pragma unroll
    for (int off = 1; off < 64; off <<= 1) {
      unsigned long long o0 = __shfl_xor(K0, off, 64);
      unsigned long long o1 = __shfl_xor(K1, off, 64);
      K0 = (o0 > K0) ? o0 : K0;                  // keys unique (m packed) -> no tie
      K1 = (o1 > K1) ? o1 : K1;
    }
    cl0 = (K0 == myK0) ? bc0 : 0xFFFFFFFFu;
    cl1 = (K1 == myK1) ? bc1 : 0xFFFFFFFFu;
    if (lane == it) {
      winm0 = 1023 - (int)(unsigned)(K0 & 0xFFFFFFFFull);
      winm1 = 1023 - (int)(unsigned)(K1 & 0xFFFFFFFFull);
    }
  }
  if (lane < KNN) {
    idxo[(b*NPTS + row0)*KNN + lane] = winm0;
    idxo[(b*NPTS + row1)*KNN + lane] = winm1;
  }
}

// fused F+D linear: yAp/yBp/yAd/yBd from packed w4 [i][o][4] = {aF,bF,aD,bD}
__global__ __launch_bounds__(256) void k_linear4(const float* __restrict__ xin, int bsx,
                                                 const float* __restrict__ w4, int DIN,
                                                 float* __restrict__ yAp, float* __restrict__ yBp,
                                                 float* __restrict__ yAd, float* __restrict__ yBd) {
  int tid = threadIdx.x;
  int o = tid & 63, ns = tid >> 6;
  int b = blockIdx.y / 3, v = blockIdx.y % 3;
  int n0 = blockIdx.x * 32 + ns * 8;
  const float* xb = xin + (size_t)b*bsx + v*NPTS + n0;
  float aF[8], bF[8], aD[8], bD[8];
  #pragma unroll
  for (int j = 0; j < 8; ++j) { aF[j] = 0.f; bF[j] = 0.f; aD[j] = 0.f; bD[j] = 0.f; }
  #pragma unroll 4
  for (int i = 0; i < DIN; ++i) {
    float4 wv  = *(const float4*)&w4[(i << 8) + (o << 2)];
    float4 xlo = *(const float4*)&xb[i*N3];
    float4 xhi = *(const float4*)&xb[i*N3 + 4];
    float xv[8] = {xlo.x, xlo.y, xlo.z, xlo.w, xhi.x, xhi.y, xhi.z, xhi.w};
    #pragma unroll
    for (int j = 0; j < 8; ++j) {
      aF[j] = fmaf(wv.x, xv[j], aF[j]);
      bF[j] = fmaf(wv.y, xv[j], bF[j]);
      aD[j] = fmaf(wv.z, xv[j], aD[j]);
      bD[j] = fmaf(wv.w, xv[j], bD[j]);
    }
  }
  int base = ((b*3 + v)*NPTS + n0)*64 + o;
  #pragma unroll
  for (int j = 0; j < 8; ++j) {
    yAp[base + j*64] = aF[j];
    yBp[base + j*64] = bF[j];
    yAd[base + j*64] = aD[j];
    yBd[base + j*64] = bD[j];
  }
}

// per-channel sum/sumsq of ||p||+eps; 2048 blocks, XCD-batch swizzle
__global__ __launch_bounds__(256) void k_stats2(const float* __restrict__ yAp, const float* __restrict__ yBp,
                                                const int* __restrict__ idxo, float* __restrict__ statsL) {
  __shared__ float rs[256], rss[256];
  int tid = threadIdx.x; int o = tid & 63, w = tid >> 6;
  int blk = blockIdx.x;
  int wg = ((blk & 7) << 8) | (blk >> 3);
  int b = wg >> 8;
  int n = ((wg & 255) << 2) + w;
  const int* ir = idxo + (b*NPTS + n)*KNN;
  int4 ir0 = *(const int4*)&ir[0],  ir1 = *(const int4*)&ir[4];
  int4 ir2 = *(const int4*)&ir[8],  ir3 = *(const int4*)&ir[12];
  int4 ir4 = *(const int4*)&ir[16];
  int mm[20] = {ir0.x,ir0.y,ir0.z,ir0.w, ir1.x,ir1.y,ir1.z,ir1.w,
                ir2.x,ir2.y,ir2.z,ir2.w, ir3.x,ir3.y,ir3.z,ir3.w,
                ir4.x,ir4.y,ir4.z,ir4.w};
  int i0 = (b*3*NPTS + n)*64 + o;
  float c0 = yBp[i0], c1 = yBp[i0 + NPTS*64], c2 = yBp[i0 + 2*NPTS*64];
  float s = 0.f, ss = 0.f;
  #pragma unroll
  for (int kk = 0; kk < KNN; ++kk) {
    int m = mm[kk];
    int gg = (b*3*NPTS + m)*64 + o;
    float p0 = yAp[gg] + c0;
    float p1 = yAp[gg + NPTS*64] + c1;
    float p2 = yAp[gg + 2*NPTS*64] + c2;
    float nrm = sqrtf(p0*p0 + p1*p1 + p2*p2) + 1e-6f;
    s += nrm; ss = fmaf(nrm, nrm, ss);
  }
  rs[tid] = s; rss[tid] = ss;
  __syncthreads();
  if (tid < 64) {
    float a  = rs[tid]  + rs[tid+64]  + rs[tid+128]  + rs[tid+192];
    float as = rss[tid] + rss[tid+64] + rss[tid+128] + rss[tid+192];
    atomicAdd(&statsL[tid], a);
    atomicAdd(&statsL[128 + tid], as);
  }
}

// BN + directional LeakyReLU + mean over k -> xfeat slice (XCD-batch swizzle)
__global__ __launch_bounds__(256) void k_apply(const float* __restrict__ yAp, const float* __restrict__ yBp,
                                               const float* __restrict__ yAd, const float* __restrict__ yBd,
                                               const int* __restrict__ idxo, const float* __restrict__ statsL,
                                               const float* __restrict__ bnw, const float* __restrict__ bnb,
                                               float* __restrict__ xfeat, int coff) {
  int tid = threadIdx.x; int o = tid & 63, w = tid >> 6;
  int blk = blockIdx.x;
  int wg = ((blk & 7) << 8) | (blk >> 3);
  int b = wg >> 8;
  int n = ((wg & 255) << 2) + w;
  const float cntInv = 1.f / 163840.f;
  float mean = statsL[o] * cntInv;
  float var  = statsL[128 + o] * cntInv - mean*mean;
  float istd = rsqrtf(var + 1e-5f);
  float wN = bnw[o], bN = bnb[o];
  int i0 = (b*3*NPTS + n)*64 + o;
  float cp0 = yBp[i0], cp1 = yBp[i0 + NPTS*64], cp2 = yBp[i0 + 2*NPTS*64];
  float cd0 = yBd[i0], cd1 = yBd[i0 + NPTS*64], cd2 = yBd[i0 + 2*NPTS*64];
  const int* ir = idxo + (b*NPTS + n)*KNN;
  int4 ir0 = *(const int4*)&ir[0],  ir1 = *(const int4*)&ir[4];
  int4 ir2 = *(const int4*)&ir[8],  ir3 = *(const int4*)&ir[12];
  int4 ir4 = *(const int4*)&ir[16];
  int mm[20] = {ir0.x,ir0.y,ir0.z,ir0.w, ir1.x,ir1.y,ir1.z,ir1.w,
                ir2.x,ir2.y,ir2.z,ir2.w, ir3.x,ir3.y,ir3.z,ir3.w,
                ir4.x,ir4.y,ir4.z,ir4.w};
  float a0 = 0.f, a1 = 0.f, a2 = 0.f;
  #pragma unroll
  for (int kk = 0; kk < KNN; ++kk) {
    int m = mm[kk];
    int gg = (b*3*NPTS + m)*64 + o;
    float p0 = yAp[gg] + cp0, p1 = yAp[gg + NPTS*64] + cp1, p2 = yAp[gg + 2*NPTS*64] + cp2;
    float d0 = yAd[gg] + cd0, d1 = yAd[gg + NPTS*64] + cd1, d2 = yAd[gg + 2*NPTS*64] + cd2;
    float nrm = sqrtf(p0*p0 + p1*p1 + p2*p2) + 1e-6f;
    float sc = ((nrm - mean)*istd*wN + bN) / nrm;
    p0 *= sc; p1 *= sc; p2 *= sc;
    float dot = p0*d0 + p1*d1 + p2*d2;
    float dsq = d0*d0 + d1*d1 + d2*d2;
    float coef = (dot < 0.f) ? (0.8f * dot / (dsq + 1e-6f)) : 0.f;
    a0 += p0 - coef*d0; a1 += p1 - coef*d1; a2 += p2 - coef*d2;
  }
  int ob = ((b*CHT + coff + o)*3)*NPTS + n;
  xfeat[ob]          = a0 * 0.05f;
  xfeat[ob + NPTS]   = a1 * 0.05f;
  xfeat[ob + 2*NPTS] = a2 * 0.05f;
}

// pF = wcf * cat (16-n LDS tile, 1536 blocks for occupancy); dF fused
__global__ __launch_bounds__(256) void k_pF4(const float* __restrict__ xfeat, const float* __restrict__ wT,
                                             const float* __restrict__ wcd,
                                             float* __restrict__ pF, float* __restrict__ dF) {
  __shared__ float xs[256][16];          // 16 KB
  __shared__ float dpart[16][16];
  int tid = threadIdx.x;
  int b = blockIdx.y / 3, v = blockIdx.y % 3;
  int n0 = blockIdx.x * 16;
  const float* xb = xfeat + (size_t)b*BSX + v*NPTS + n0;
  #pragma unroll
  for (int u = 0; u < 4; ++u) {
    int e = tid + (u << 8);              // 0..1023
    int i = e >> 2, sl = (e & 3) << 2;
    *(float4*)&xs[i][sl] = *(const float4*)&xb[(size_t)i*N3 + sl];
  }
  __syncthreads();
  int o = tid & 127, h = tid >> 7;       // h: n-half (8 each)
  float a[8];
  #pragma unroll
  for (int j = 0; j < 8; ++j) a[j] = 0.f;
  for (int i = 0; i < 256; ++i) {
    float wv = wT[i*128 + o];
    #pragma unroll
    for (int q = 0; q < 2; ++q) {
      float4 xv = *(const float4*)&xs[i][h*8 + q*4];
      a[q*4+0] = fmaf(wv, xv.x, a[q*4+0]);
      a[q*4+1] = fmaf(wv, xv.y, a[q*4+1]);
      a[q*4+2] = fmaf(wv, xv.z, a[q*4+2]);
      a[q*4+3] = fmaf(wv, xv.w, a[q*4+3]);
    }
  }
  int base = ((b*3 + v)*NPTS + n0 + h*8)*128 + o;
  #pragma unroll
  for (int j = 0; j < 8; ++j) pF[base + j*128] = a[j];
  int nn = tid & 15, gI = tid >> 4;      // 16 groups x 16 i
  float dp = 0.f;
  for (int i = gI*16; i < gI*16 + 16; ++i) dp = fmaf(wcd[i], xs[i][nn], dp);
  dpart[gI][nn] = dp;
  __syncthreads();
  if (tid < 16) {
    float aa = 0.f;
    #pragma unroll
    for (int gq = 0; gq < 16; ++gq) aa += dpart[gq][tid];
    dF[(b*3 + v)*NPTS + n0 + tid] = aa;
  }
}

__global__ __launch_bounds__(256) void k_statsF2(const float* __restrict__ pF, float* __restrict__ statsF) {
  int tid = threadIdx.x; int o = tid & 127, half = tid >> 7;
  int blk = blockIdx.x;
  int b = blk >> 6, n0 = (blk & 63) << 4;
  float s = 0.f, ss = 0.f;
  for (int j = 0; j < 8; ++j) {
    int n = n0 + half + (j << 1);
    int g = (b*3*NPTS + n)*128 + o;
    float p0 = pF[g], p1 = pF[g + NPTS*128], p2 = pF[g + 2*NPTS*128];
    float nrm = sqrtf(p0*p0 + p1*p1 + p2*p2) + 1e-6f;
    s += nrm; ss = fmaf(nrm, nrm, ss);
  }
  atomicAdd(&statsF[o], s);
  atomicAdd(&statsF[128 + o], ss);
}

__global__ __launch_bounds__(256) void k_final2(const float* __restrict__ pF, const float* __restrict__ dF,
                                                const float* __restrict__ statsF,
                                                const float* __restrict__ bncw, const float* __restrict__ bncb,
                                                float* __restrict__ out) {
  int tid = threadIdx.x; int o = tid & 127, half = tid >> 7;
  int blk = blockIdx.x;
  int b = blk >> 5, n0 = (blk & 31) << 5;
  const float cntInv = 1.f / 8192.f;
  float mean = statsF[o] * cntInv;
  float var  = statsF[128 + o] * cntInv - mean*mean;
  float istd = rsqrtf(var + 1e-5f);
  float wN = bncw[o], bN = bncb[o];
  float a0 = 0.f, a1 = 0.f, a2 = 0.f;
  for (int j = 0; j < 16; ++j) {
    int n = n0 + half + (j << 1);
    int g = (b*3*NPTS + n)*128 + o;
    float p0 = pF[g], p1 = pF[g + NPTS*128], p2 = pF[g + 2*NPTS*128];
    int dg = b*N3 + n;
    float d0 = dF[dg], d1 = dF[dg + NPTS], d2 = dF[dg + 2*NPTS];
    float nrm = sqrtf(p0*p0 + p1*p1 + p2*p2) + 1e-6f;
    float sc = ((nrm - mean)*istd*wN + bN) / nrm;
    p0 *= sc; p1 *= sc; p2 *= sc;
    float dot = p0*d0 + p1*d1 + p2*d2;
    float dsq = d0*d0 + d1*d1 + d2*d2;
    float coef = (dot < 0.f) ? (0.8f * dot / (dsq + 1e-6f)) : 0.f;
    a0 += p0 - coef*d0; a1 += p1 - coef*d1; a2 += p2 - coef*d2;
  }
  float scl = 1.f / 1024.f;
  int ob = (b*128 + o)*3;
  atomicAdd(&out[ob],     a0*scl);
  atomicAdd(&out[ob + 1], a1*scl);
  atomicAdd(&out[ob + 2], a2*scl);
}

extern "C" void kernel_launch(void* const* d_in, const int* in_sizes, int n_in,
                              void* d_out, int out_size, void* d_ws, size_t ws_size,
                              hipStream_t stream) {
  (void)in_sizes; (void)n_in; (void)ws_size;
  const float* x = (const float*)d_in[0];
  const float* bnW[4] = {(const float*)d_in[3],  (const float*)d_in[7],
                         (const float*)d_in[11], (const float*)d_in[15]};
  const float* bnB[4] = {(const float*)d_in[4],  (const float*)d_in[8],
                         (const float*)d_in[12], (const float*)d_in[16]};
  const float* wcf  = (const float*)d_in[17];
  const float* wcd  = (const float*)d_in[18];
  const float* bncw = (const float*)d_in[19];
  const float* bncb = (const float*)d_in[20];

  float* ws    = (float*)d_ws;
  float* x0    = ws + OFF_X0;
  float* xfeat = ws + OFF_XFEAT;
  float* yAp   = ws + OFF_YAP;
  float* yBp   = ws + OFF_YBP;
  float* yAd   = ws + OFF_YAD;
  float* yBd   = ws + OFF_YBD;
  float* pF    = ws + OFF_PF;   // aliases yAp/yBp (dead by then)
  float* dF    = ws + OFF_DF;   // aliases yAd
  float* xx    = ws + OFF_XX;
  float* wT    = ws + OFF_WCFT;
  float* stats = ws + OFF_STATS;
  int*   idx   = (int*)(ws + OFF_IDX);
  float* w4    = ws + OFF_W4;

  k_prep<<<41, 256, 0, stream>>>(x,
      (const float*)d_in[1], (const float*)d_in[2],
      (const float*)d_in[5], (const float*)d_in[6],
      (const float*)d_in[9], (const float*)d_in[10],
      (const float*)d_in[13], (const float*)d_in[14],
      wcf, x0, w4, wT, stats, (float*)d_out, out_size);

  for (int L = 0; L < 4; ++L) {
    const float* fin = (L == 0) ? x0 : (xfeat + (L-1)*64*N3);
    int bs = (L == 0) ? N3 : BSX;
    int D  = (L == 0) ? 3 : 192;
    int DIN = (L == 0) ? 1 : 64;
    k_xx3<<<NB*NPTS/16, 256, 0, stream>>>(fin, bs, D, xx);
    k_knn2<<<512, 512, 0, stream>>>(fin, bs, D, xx, idx);
    k_linear4<<<dim3(32, 24), 256, 0, stream>>>(fin, bs, w4 + L*16384, DIN,
                                                yAp, yBp, yAd, yBd);
    k_stats2<<<2048, 256, 0, stream>>>(yAp, yBp, idx, stats + L*256);
    k_apply<<<2048, 256, 0, stream>>>(yAp, yBp, yAd, yBd, idx, stats + L*256,
                                      bnW[L], bnB[L], xfeat, L*64);
  }

  k_pF4<<<dim3(64, 24), 256, 0, stream>>>(xfeat, wT, wcd, pF, dF);
  k_statsF2<<<512, 256, 0, stream>>>(pF, stats + 4*256);
  k_final2<<<256, 256, 0, stream>>>(pF, dF, stats + 4*256, bncw, bncb, (float*)d_out);
}